// Round 4
// baseline (246.576 us; speedup 1.0000x reference)
//
#include <hip/hip_runtime.h>

// OrthogonalLayer2D via Cholesky-QR (== classical Gram-Schmidt):
//   x reshaped (N=8, MC=4096, D=1024). Per mc: G = V V^T (8x8), L = chol(G),
//   B = L^{-1} V, row i scaled by 1/L[i][i]; degenerate pivot -> 0 (NaN->0 rule).
// One 128-thread block per mc; 8 elems/thread in registers. Wave reduction via
// DPP VALU adds (row_shr/row_bcast) instead of __shfl_xor -> no ds_bpermute
// latency chains (the R1/R2 bottleneck). Single barrier, 36-float LDS combine.

#define MC   4096
#define DIM  1024
#define NV   8
#define TPB  128          // 2 waves
#define E    8            // elems per thread; two coalesced float4 chunks
#define IDX(i,j) ((i)*((i)+1)/2+(j))   // packed lower-tri index, i >= j

typedef float f32x4 __attribute__((ext_vector_type(4)));   // native vec for NT stores

// x + dpp_moved(x): one step of the gfx9 wave-sum ladder. CTRL/ROWM constant.
template <int CTRL, int ROWM>
__device__ __forceinline__ float dpp_add(float x) {
    const int m = __builtin_amdgcn_update_dpp(
        0, __float_as_int(x), CTRL, ROWM, 0xf, false);
    return x + __int_as_float(m);
}

// Full 64-lane sum; total lands in lane 63. Pure VALU (v_add + v_mov_dpp).
__device__ __forceinline__ float wave_sum(float x) {
    x = dpp_add<0x111, 0xf>(x);   // row_shr:1
    x = dpp_add<0x112, 0xf>(x);   // row_shr:2
    x = dpp_add<0x114, 0xf>(x);   // row_shr:4
    x = dpp_add<0x118, 0xf>(x);   // row_shr:8  -> lane15 of each row = row sum
    x = dpp_add<0x142, 0xa>(x);   // row_bcast:15 into rows 1,3
    x = dpp_add<0x143, 0xc>(x);   // row_bcast:31 into rows 2,3 -> lane63 total
    return x;
}

__global__ __launch_bounds__(TPB) void gs_kernel(const float* __restrict__ x,
                                                 float* __restrict__ out) {
    const int mc   = blockIdx.x;
    const int t    = threadIdx.x;
    const int lane = t & 63;
    const int wave = t >> 6;

    __shared__ float red[2][36];

    const size_t strideN = (size_t)MC * DIM;
    const size_t base    = (size_t)mc * DIM;

    // Load: two half-chunks so every float4 load is lane-contiguous.
    float v[NV][E];
#pragma unroll
    for (int n = 0; n < NV; ++n) {
        const float4 a = *reinterpret_cast<const float4*>(x + n * strideN + base + (size_t)t * 4);
        const float4 b = *reinterpret_cast<const float4*>(x + n * strideN + base + 512 + (size_t)t * 4);
        v[n][0] = a.x; v[n][1] = a.y; v[n][2] = a.z; v[n][3] = a.w;
        v[n][4] = b.x; v[n][5] = b.y; v[n][6] = b.z; v[n][7] = b.w;
    }

    // 36 Gram partials (lower triangle incl. diagonal), 36-way ILP.
    float g[36];
#pragma unroll
    for (int i = 0; i < NV; ++i) {
#pragma unroll
        for (int j = 0; j <= i; ++j) {
            float s = 0.0f;
#pragma unroll
            for (int e = 0; e < E; ++e) s += v[i][e] * v[j][e];
            g[IDX(i, j)] = s;
        }
    }

    // Wave reduce all 36 values on the VALU pipe (no LDS latency chains).
#pragma unroll
    for (int k = 0; k < 36; ++k) g[k] = wave_sum(g[k]);

    // Cross-wave combine: lane 63 holds each wave's sums.
    if (lane == 63) {
#pragma unroll
        for (int k = 0; k < 36; ++k) red[wave][k] = g[k];
    }
    __syncthreads();
#pragma unroll
    for (int k = 0; k < 36; ++k) g[k] = red[0][k] + red[1][k];   // broadcast reads

    // In-register 8x8 Cholesky: g becomes L (packed lower-tri). Uniform work.
    float rdiag[NV];   // 1/L[i][i], 0 if degenerate (replicates NaN->0 rule)
#pragma unroll
    for (int i = 0; i < NV; ++i) {
#pragma unroll
        for (int j = 0; j < i; ++j) {
            float s = g[IDX(i, j)];
#pragma unroll
            for (int p = 0; p < NV; ++p) {
                if (p >= j) break;
                s -= g[IDX(i, p)] * g[IDX(j, p)];
            }
            g[IDX(i, j)] = s * rdiag[j];
        }
        float d = g[IDX(i, i)];
#pragma unroll
        for (int p = 0; p < NV; ++p) {
            if (p >= i) break;
            d -= g[IDX(i, p)] * g[IDX(i, p)];
        }
        g[IDX(i, i)] = (d > 0.0f) ? sqrtf(d) : 0.0f;
        rdiag[i]     = (d > 0.0f) ? rsqrtf(d) : 0.0f;
    }

    // Forward substitution: v[i] <- (v[i] - sum_{j<i} L[i][j] * b[j]) * rdiag[i].
#pragma unroll
    for (int i = 0; i < NV; ++i) {
#pragma unroll
        for (int j = 0; j < NV; ++j) {
            if (j >= i) break;
            const float lij = g[IDX(i, j)];
#pragma unroll
            for (int e = 0; e < E; ++e) v[i][e] -= lij * v[j][e];
        }
        const float r = rdiag[i];
#pragma unroll
        for (int e = 0; e < E; ++e) v[i][e] *= r;
    }

    // Store: non-temporal (output never re-read; keep input resident in L3).
#pragma unroll
    for (int n = 0; n < NV; ++n) {
        f32x4* p0 = reinterpret_cast<f32x4*>(out + n * strideN + base + (size_t)t * 4);
        f32x4* p1 = reinterpret_cast<f32x4*>(out + n * strideN + base + 512 + (size_t)t * 4);
        f32x4 a; a.x = v[n][0]; a.y = v[n][1]; a.z = v[n][2]; a.w = v[n][3];
        f32x4 b; b.x = v[n][4]; b.y = v[n][5]; b.z = v[n][6]; b.w = v[n][7];
        __builtin_nontemporal_store(a, p0);
        __builtin_nontemporal_store(b, p1);
    }
}

extern "C" void kernel_launch(void* const* d_in, const int* in_sizes, int n_in,
                              void* d_out, int out_size, void* d_ws, size_t ws_size,
                              hipStream_t stream) {
    const float* x = (const float*)d_in[0];
    float* out = (float*)d_out;
    gs_kernel<<<MC, TPB, 0, stream>>>(x, out);
}